// Round 12
// baseline (596.492 us; speedup 1.0000x reference)
//
#include <hip/hip_runtime.h>
#include <hip/hip_fp16.h>

typedef _Float16 f16_t;
typedef __attribute__((ext_vector_type(8))) _Float16 f16x8;
typedef __attribute__((ext_vector_type(4))) _Float16 f16x4;
typedef __attribute__((ext_vector_type(4))) float f32x4;
typedef __attribute__((ext_vector_type(16))) float f32x16;

__device__ __forceinline__ void gload_lds16(const void* g, void* lds) {
    __builtin_amdgcn_global_load_lds(
        (const __attribute__((address_space(1))) unsigned int*)g,
        (__attribute__((address_space(3))) unsigned int*)lds,
        16, 0, 0);
}

__device__ __forceinline__ float sigmoidf_(float v) {
    return 1.0f / (1.0f + expf(-v));
}

// ---------------------------------------------------------------------------
// Gating: one block per sample b. Output stride padded to 12032 (zeros in pad)
// ---------------------------------------------------------------------------
__global__ __launch_bounds__(256) void gate_kernel(
    const float* __restrict__ x, const float* __restrict__ conv_w,
    const float* __restrict__ F_w, f16_t* __restrict__ G) {
    __shared__ alignas(16) float xs[12000];
    __shared__ float part[240];
    __shared__ float mW[120];
    __shared__ float sv[10];
    __shared__ float tv[40];
    __shared__ float gsv[3][10];
    __shared__ float gwv[3][40];

    const int t = threadIdx.x;
    const long b = blockIdx.x;
    const float4* xp = (const float4*)(x + b * 12000);
    float4* xs4 = (float4*)xs;
    for (int i = t; i < 3000; i += 256) xs4[i] = xp[i];
    __syncthreads();

    if (t < 240) {
        int c = t / 80, h = (t % 80) / 8, g = t % 8;
        const float* p = xs + c * 4000 + h * 40 + g * 5;
        float s = 0.f;
        #pragma unroll
        for (int d = 0; d < 10; ++d)
            #pragma unroll
            for (int j = 0; j < 5; ++j) s += p[d * 400 + j];
        part[t] = s;
    }
    if (t < 120) {
        int c = t / 40, w = t % 40;
        const float* p = xs + c * 4000 + w;
        float s = 0.f;
        #pragma unroll
        for (int d = 0; d < 10; ++d)
            #pragma unroll
            for (int h = 0; h < 10; ++h) s += p[d * 400 + h * 40];
        mW[t] = s;
    }
    __syncthreads();
    if (t < 10) {
        float a = 0.f;
        #pragma unroll
        for (int c = 0; c < 3; ++c) {
            float m = 0.f;
            #pragma unroll
            for (int g = 0; g < 8; ++g) m += part[c * 80 + t * 8 + g];
            a += conv_w[c] * (m * (1.f / 400.f));
        }
        sv[t] = fmaxf(a, 0.f);
    }
    if (t < 40) {
        float a = 0.f;
        #pragma unroll
        for (int c = 0; c < 3; ++c) a += conv_w[c] * (mW[c * 40 + t] * (1.f / 100.f));
        tv[t] = fmaxf(a, 0.f);
    }
    __syncthreads();
    if (t < 30) { int c = t / 10, k = t % 10; gsv[c][k] = sigmoidf_(F_w[c] * sv[k]); }
    if (t < 120) { int c = t / 40, w = t % 40; gwv[c][w] = sigmoidf_(F_w[c] * tv[w]); }
    __syncthreads();

    f16x4* Gp = (f16x4*)(G + b * 12032);
    for (int i = t; i < 3000; i += 256) {
        int flat = i * 4;
        int c = flat / 4000, rem = flat % 4000;
        int d = rem / 400, rem2 = rem % 400;
        int h = rem2 / 40, w0 = rem2 % 40;
        float gdh = gsv[c][d] * gsv[c][h];
        float4 v = xs4[i];
        f16x4 o;
        o[0] = (f16_t)(v.x * gdh * gwv[c][w0 + 0]);
        o[1] = (f16_t)(v.y * gdh * gwv[c][w0 + 1]);
        o[2] = (f16_t)(v.z * gdh * gwv[c][w0 + 2]);
        o[3] = (f16_t)(v.w * gdh * gwv[c][w0 + 3]);
        Gp[i] = o;
    }
    if (t < 8) Gp[3000 + t] = (f16x4){};   // zero pad K 12000->12032
}

// ---------------------------------------------------------------------------
// fp32 -> fp16 row convert with K padding 12000 -> 12032 (one block per row)
// ---------------------------------------------------------------------------
__global__ __launch_bounds__(256) void cvt_f16_pad(
    const float* __restrict__ in, f16_t* __restrict__ out) {
    const long r = blockIdx.x;
    const float4* ip = (const float4*)(in + r * 12000);
    f16x4* op = (f16x4*)(out + r * 12032);
    for (int i = threadIdx.x; i < 3000; i += 256) {
        float4 v = ip[i];
        f16x4 o;
        o[0] = (f16_t)v.x; o[1] = (f16_t)v.y; o[2] = (f16_t)v.z; o[3] = (f16_t)v.w;
        op[i] = o;
    }
    if (threadIdx.x < 8) op[3000 + threadIdx.x] = (f16x4){};
}

// ---------------------------------------------------------------------------
// fp32 -> fp16 convert, flat (n4 float4 chunks) — for w2
// ---------------------------------------------------------------------------
__global__ __launch_bounds__(256) void cvt_f16(
    const float* __restrict__ in, f16_t* __restrict__ out, long n4) {
    long stride = (long)gridDim.x * 256;
    for (long i = (long)blockIdx.x * 256 + threadIdx.x; i < n4; i += stride) {
        float4 v = ((const float4*)in)[i];
        f16x4 o;
        o[0] = (f16_t)v.x; o[1] = (f16_t)v.y; o[2] = (f16_t)v.z; o[3] = (f16_t)v.w;
        ((f16x4*)out)[i] = o;
    }
}

// ---------------------------------------------------------------------------
// GEMM1: r7 structure with 32x32x16 MFMAs (halved instruction count, +15%
// MFMA ceiling 2075->2382 TF). 256x256 tile, BK=64, 8 waves (2Mx4N), K-HALF
// phases, counted vmcnt(4) (T4), T2 swizzle, setprio, compiler-scheduled lgkm.
// Fragment mapping (32x32x16): A/B lane l: row = l&31, k = (l>>5)*8 + 0..7;
// C/D: col = lane&31, row = (reg&3) + 8*(reg>>2) + 4*(lane>>5)  [m74/m101].
// Swizzled read: slot u=(kq*2+lh), u' = u ^ ((l31>>1)&3) (rbases %32==0).
// C[M,N] = relu(A[M,K2] @ B[N,K2]^T + bias[N]), f16 in, f16 out.
// ---------------------------------------------------------------------------
__global__ __launch_bounds__(512, 2) void gemm1_kphase(
    const f16_t* __restrict__ A, const f16_t* __restrict__ B,
    const float* __restrict__ bias, f16_t* __restrict__ C,
    int M, int N, int K2, int NT) {
    __shared__ alignas(16) f16_t lds[65536];   // 128 KiB: 2 bufs x 32768 elems
    const int t = threadIdx.x;
    const int lane = t & 63, w = t >> 6;
    const int wr = w >> 2, wc = w & 3;
    const int l31 = lane & 31, lh = lane >> 5;
    const long tileM = (long)blockIdx.y * 256;
    const long tileN = (long)blockIdx.x * 256;
    const long lK2 = K2;

    const int srow = t >> 2;                           // 0..127
    const int gs8 = ((t & 3) ^ ((t >> 3) & 3)) * 8;    // swizzled global k-slot
    auto stage_half = [&](int dst, int ph, long kk) {
        f16_t* dA = lds + dst * 32768 + ph * 8192;
        f16_t* dB = dA + 16384;
        gload_lds16(A + (tileM + srow) * lK2 + kk + gs8, dA + t * 8);
        gload_lds16(A + (tileM + srow + 128) * lK2 + kk + gs8, dA + 4096 + t * 8);
        gload_lds16(B + (tileN + srow) * lK2 + kk + gs8, dB + t * 8);
        gload_lds16(B + (tileN + srow + 128) * lK2 + kk + gs8, dB + 4096 + t * 8);
    };

    // fragment read offsets (32x32 frags): row = rbase + l31, 16B-slot
    // u' = (kq*2 + lh) ^ s32 where s32 = (l31>>1)&3
    const int s32 = (l31 >> 1) & 3;
    const int ksl0 = ((0 * 2 + lh) ^ s32) * 8;   // kq=0
    const int ksl1 = ((1 * 2 + lh) ^ s32) * 8;   // kq=1
    const int arow = (wr * 128 + l31) * 32;
    const int brow = (wc * 64 + l31) * 32;

    f32x16 acc[4][2] = {};   // [row-group g][col-group n], 128 VGPRs

    stage_half(0, 0, 0);
    stage_half(0, 1, 32);
    asm volatile("s_waitcnt vmcnt(4)" ::: "memory");
    __builtin_amdgcn_s_barrier();

    for (int kt = 0; kt < NT; ++kt) {
        const int c = kt & 1;
        const f16_t* bufc = lds + c * 32768;
        const bool more = (kt + 1 < NT);
        #pragma unroll
        for (int ph = 0; ph < 2; ++ph) {
            const f16_t* pa = bufc + ph * 8192;
            const f16_t* pb = bufc + 16384 + ph * 8192;
            // --- pipeline-ordered fragment reads (consumers first) ---
            f16x8 b00 = *(const f16x8*)(pb + brow + ksl0);           // n=0,kq=0
            f16x8 a0[4];
            #pragma unroll
            for (int g = 0; g < 4; ++g)
                a0[g] = *(const f16x8*)(pa + arow + g * 1024 + ksl0);
            f16x8 b10 = *(const f16x8*)(pb + brow + 1024 + ksl0);    // n=1,kq=0
            f16x8 b01 = *(const f16x8*)(pb + brow + ksl1);           // n=0,kq=1
            f16x8 a1[4];
            #pragma unroll
            for (int g = 0; g < 4; ++g)
                a1[g] = *(const f16x8*)(pa + arow + g * 1024 + ksl1);
            f16x8 b11 = *(const f16x8*)(pb + brow + 1024 + ksl1);    // n=1,kq=1
            if (more) stage_half(c ^ 1, ph, (long)(kt + 1) * 64 + ph * 32);
            __builtin_amdgcn_s_setprio(1);
            // --- 16 MFMAs: kq=0 then kq=1, distinct acc within each kq ---
            #pragma unroll
            for (int g = 0; g < 4; ++g)
                acc[g][0] = __builtin_amdgcn_mfma_f32_32x32x16_f16(
                    a0[g], b00, acc[g][0], 0, 0, 0);
            #pragma unroll
            for (int g = 0; g < 4; ++g)
                acc[g][1] = __builtin_amdgcn_mfma_f32_32x32x16_f16(
                    a0[g], b10, acc[g][1], 0, 0, 0);
            #pragma unroll
            for (int g = 0; g < 4; ++g)
                acc[g][0] = __builtin_amdgcn_mfma_f32_32x32x16_f16(
                    a1[g], b01, acc[g][0], 0, 0, 0);
            #pragma unroll
            for (int g = 0; g < 4; ++g)
                acc[g][1] = __builtin_amdgcn_mfma_f32_32x32x16_f16(
                    a1[g], b11, acc[g][1], 0, 0, 0);
            __builtin_amdgcn_s_setprio(0);
            if (more) asm volatile("s_waitcnt vmcnt(4)" ::: "memory");
            else      asm volatile("s_waitcnt vmcnt(0)" ::: "memory");
            __builtin_amdgcn_s_barrier();
        }
    }

    // epilogue: bias + relu, f16 out.
    // col = tileN + wc*64 + n*32 + l31; row = tileM + wr*128 + g*32 + crow,
    // crow = (reg&3) + 8*(reg>>2) + 4*lh
    #pragma unroll
    for (int n = 0; n < 2; ++n) {
        long col = tileN + wc * 64 + n * 32 + l31;
        float bia = bias[col];
        #pragma unroll
        for (int g = 0; g < 4; ++g) {
            long rowb = tileM + wr * 128 + g * 32 + 4 * lh;
            #pragma unroll
            for (int reg = 0; reg < 16; ++reg) {
                long row = rowb + (reg & 3) + 8 * (reg >> 2);
                float o = fmaxf(acc[g][n][reg] + bia, 0.f);
                C[row * (long)N + col] = (f16_t)o;
            }
        }
    }
}

// ---------------------------------------------------------------------------
// GEMM2 split-K (m97 structure, 64x128 tile, BK=32): each K-chunk writes RAW
// partial sums (no bias/relu) to z2p[kc]. Grid (N/128, M/64, 2) = 512 blocks
// -> 2 blocks/CU -> cross-block overlap hides the per-iter vmcnt drain.
// ---------------------------------------------------------------------------
__global__ __launch_bounds__(256) void gemm2_splitk(
    const f16_t* __restrict__ A, const f16_t* __restrict__ B,
    float* __restrict__ Pp, int M, int N, int K, int KC) {
    __shared__ alignas(16) f16_t As[64 * 32];
    __shared__ alignas(16) f16_t Bs[128 * 32];
    const int t = threadIdx.x;
    const int lane = t & 63, wid = t >> 6;
    const int wr = wid >> 1, wc = wid & 1;
    const int l15 = lane & 15, lg = lane >> 4;
    const long rowA0 = (long)blockIdx.y * 64;
    const long colB0 = (long)blockIdx.x * 128;
    const int kc = blockIdx.z;
    const int k0 = kc * KC, k1 = k0 + KC;

    const int eA = t * 8;
    const int rA = eA >> 5, kA = eA & 31;
    const int eB0 = t * 8;
    const int rB0 = eB0 >> 5, kB0 = eB0 & 31;
    const int eB1 = eB0 + 2048;
    const int rB1 = eB1 >> 5, kB1 = eB1 & 31;

    int aoff[2], boff[4];
    #pragma unroll
    for (int m = 0; m < 2; ++m) aoff[m] = (wr * 32 + m * 16 + l15) * 32 + lg * 8;
    #pragma unroll
    for (int n = 0; n < 4; ++n) boff[n] = (wc * 64 + n * 16 + l15) * 32 + lg * 8;

    f32x4 acc[2][4] = {};

    for (int kk = k0; kk < k1; kk += 32) {
        __syncthreads();
        gload_lds16(A + (rowA0 + rA) * (long)K + kk + kA, As + eA);
        gload_lds16(B + (colB0 + rB0) * (long)K + kk + kB0, Bs + eB0);
        gload_lds16(B + (colB0 + rB1) * (long)K + kk + kB1, Bs + eB1);
        __syncthreads();

        f16x8 af[2], bfv[4];
        #pragma unroll
        for (int m = 0; m < 2; ++m) af[m] = *(const f16x8*)(As + aoff[m]);
        #pragma unroll
        for (int n = 0; n < 4; ++n) bfv[n] = *(const f16x8*)(Bs + boff[n]);
        #pragma unroll
        for (int m = 0; m < 2; ++m)
            #pragma unroll
            for (int n = 0; n < 4; ++n)
                acc[m][n] = __builtin_amdgcn_mfma_f32_16x16x32_f16(
                    af[m], bfv[n], acc[m][n], 0, 0, 0);
    }

    float* P = Pp + (long)kc * M * N;
    const long rowC0 = rowA0 + wr * 32 + lg * 4;
    const long colC0 = colB0 + wc * 64 + l15;
    #pragma unroll
    for (int n = 0; n < 4; ++n) {
        long col = colC0 + n * 16;
        #pragma unroll
        for (int m = 0; m < 2; ++m) {
            #pragma unroll
            for (int r = 0; r < 4; ++r) {
                long row = rowC0 + m * 16 + r;
                P[row * (long)N + col] = acc[m][n][r];
            }
        }
    }
}

// ---------------------------------------------------------------------------
// Head: z2 = relu(sum of 2 partials + b2); out = normalize(z2 @ w3^T + b3).
// One wave per row.
// ---------------------------------------------------------------------------
__global__ __launch_bounds__(256) void head_kernel(
    const float* __restrict__ Pp, const float* __restrict__ b2,
    const float* __restrict__ w3, const float* __restrict__ b3,
    float* __restrict__ out) {
    const int lane = threadIdx.x & 63, wid = threadIdx.x >> 6;
    const long b = (long)blockIdx.x * 4 + wid;
    const float4* p0 = (const float4*)(Pp + b * 512);
    const float4* p1 = (const float4*)(Pp + 2097152L + b * 512);
    const float4* bb = (const float4*)b2;
    float4 u0 = p0[lane * 2], u1 = p0[lane * 2 + 1];
    float4 v0 = p1[lane * 2], v1 = p1[lane * 2 + 1];
    float4 c0 = bb[lane * 2], c1 = bb[lane * 2 + 1];
    float4 z0, z1;
    z0.x = fmaxf(u0.x + v0.x + c0.x, 0.f); z0.y = fmaxf(u0.y + v0.y + c0.y, 0.f);
    z0.z = fmaxf(u0.z + v0.z + c0.z, 0.f); z0.w = fmaxf(u0.w + v0.w + c0.w, 0.f);
    z1.x = fmaxf(u1.x + v1.x + c1.x, 0.f); z1.y = fmaxf(u1.y + v1.y + c1.y, 0.f);
    z1.z = fmaxf(u1.z + v1.z + c1.z, 0.f); z1.w = fmaxf(u1.w + v1.w + c1.w, 0.f);
    float d[3];
    #pragma unroll
    for (int o = 0; o < 3; ++o) {
        const float4* wp = (const float4*)(w3 + o * 512);
        float4 a0 = wp[lane * 2], a1 = wp[lane * 2 + 1];
        d[o] = z0.x * a0.x + z0.y * a0.y + z0.z * a0.z + z0.w * a0.w +
               z1.x * a1.x + z1.y * a1.y + z1.z * a1.z + z1.w * a1.w;
    }
    #pragma unroll
    for (int o = 0; o < 3; ++o)
        #pragma unroll
        for (int off = 1; off < 64; off <<= 1) d[o] += __shfl_xor(d[o], off);
    float d0 = d[0] + b3[0], d1 = d[1] + b3[1], d2 = d[2] + b3[2];
    float nrm = fmaxf(sqrtf(d0 * d0 + d1 * d1 + d2 * d2), 1e-12f);
    if (lane < 3) {
        float v = (lane == 0) ? d0 : (lane == 1) ? d1 : d2;
        out[b * 3 + lane] = v / nrm;
    }
}

// ---------------------------------------------------------------------------
// Workspace layout (bytes), max 234.9 MB:
//   G   f16 4096x12032 :           0 ..  98,566,144
//   w1h f16 4096x12032 :  98,566,144 .. 197,132,288
//   z1  f16 4096x4096  : 197,132,288 .. 230,686,720
//   w2h f16  512x4096  : 230,686,720 .. 234,881,024
//   z2p f32 2x4096x512 :           0 ..  16,777,216  (overlaps dead G)
// ---------------------------------------------------------------------------
extern "C" void kernel_launch(void* const* d_in, const int* in_sizes, int n_in,
                              void* d_out, int out_size, void* d_ws, size_t ws_size,
                              hipStream_t stream) {
    const float* x      = (const float*)d_in[0];
    const float* conv_w = (const float*)d_in[1];
    const float* F_w    = (const float*)d_in[2];
    const float* w1     = (const float*)d_in[3];
    const float* b1     = (const float*)d_in[4];
    const float* w2     = (const float*)d_in[5];
    const float* b2     = (const float*)d_in[6];
    const float* w3     = (const float*)d_in[7];
    const float* b3     = (const float*)d_in[8];
    float* out = (float*)d_out;

    char* ws = (char*)d_ws;
    f16_t* G   = (f16_t*)(ws);
    f16_t* w1h = (f16_t*)(ws + 98566144L);
    f16_t* z1  = (f16_t*)(ws + 197132288L);
    f16_t* w2h = (f16_t*)(ws + 230686720L);
    float* z2p = (float*)(ws);             // overlaps G (dead after GEMM1)

    gate_kernel<<<4096, 256, 0, stream>>>(x, conv_w, F_w, G);
    cvt_f16_pad<<<4096, 256, 0, stream>>>(w1, w1h);
    cvt_f16<<<512, 256, 0, stream>>>(w2, w2h, 524288L);
    gemm1_kphase<<<dim3(16, 16), 512, 0, stream>>>(G, w1h, b1, z1, 4096, 4096, 12032, 188);
    gemm2_splitk<<<dim3(4, 64, 2), 256, 0, stream>>>(z1, w2h, z2p, 4096, 512, 4096, 2048);
    head_kernel<<<1024, 256, 0, stream>>>(z2p, b2, w3, b3, out);
}

// Round 13
// 531.727 us; speedup vs baseline: 1.1218x; 1.1218x over previous
//
#include <hip/hip_runtime.h>
#include <hip/hip_fp16.h>

typedef _Float16 f16_t;
typedef __attribute__((ext_vector_type(8))) _Float16 f16x8;
typedef __attribute__((ext_vector_type(4))) _Float16 f16x4;
typedef __attribute__((ext_vector_type(4))) float f32x4;

__device__ __forceinline__ void gload_lds16(const void* g, void* lds) {
    __builtin_amdgcn_global_load_lds(
        (const __attribute__((address_space(1))) unsigned int*)g,
        (__attribute__((address_space(3))) unsigned int*)lds,
        16, 0, 0);
}

__device__ __forceinline__ float sigmoidf_(float v) {
    return 1.0f / (1.0f + expf(-v));
}

// ---------------------------------------------------------------------------
// Gating: one block per sample b. Output stride padded to 12032 (zeros in pad)
// ---------------------------------------------------------------------------
__global__ __launch_bounds__(256) void gate_kernel(
    const float* __restrict__ x, const float* __restrict__ conv_w,
    const float* __restrict__ F_w, f16_t* __restrict__ G) {
    __shared__ alignas(16) float xs[12000];
    __shared__ float part[240];
    __shared__ float mW[120];
    __shared__ float sv[10];
    __shared__ float tv[40];
    __shared__ float gsv[3][10];
    __shared__ float gwv[3][40];

    const int t = threadIdx.x;
    const long b = blockIdx.x;
    const float4* xp = (const float4*)(x + b * 12000);
    float4* xs4 = (float4*)xs;
    for (int i = t; i < 3000; i += 256) xs4[i] = xp[i];
    __syncthreads();

    if (t < 240) {
        int c = t / 80, h = (t % 80) / 8, g = t % 8;
        const float* p = xs + c * 4000 + h * 40 + g * 5;
        float s = 0.f;
        #pragma unroll
        for (int d = 0; d < 10; ++d)
            #pragma unroll
            for (int j = 0; j < 5; ++j) s += p[d * 400 + j];
        part[t] = s;
    }
    if (t < 120) {
        int c = t / 40, w = t % 40;
        const float* p = xs + c * 4000 + w;
        float s = 0.f;
        #pragma unroll
        for (int d = 0; d < 10; ++d)
            #pragma unroll
            for (int h = 0; h < 10; ++h) s += p[d * 400 + h * 40];
        mW[t] = s;
    }
    __syncthreads();
    if (t < 10) {
        float a = 0.f;
        #pragma unroll
        for (int c = 0; c < 3; ++c) {
            float m = 0.f;
            #pragma unroll
            for (int g = 0; g < 8; ++g) m += part[c * 80 + t * 8 + g];
            a += conv_w[c] * (m * (1.f / 400.f));
        }
        sv[t] = fmaxf(a, 0.f);
    }
    if (t < 40) {
        float a = 0.f;
        #pragma unroll
        for (int c = 0; c < 3; ++c) a += conv_w[c] * (mW[c * 40 + t] * (1.f / 100.f));
        tv[t] = fmaxf(a, 0.f);
    }
    __syncthreads();
    if (t < 30) { int c = t / 10, k = t % 10; gsv[c][k] = sigmoidf_(F_w[c] * sv[k]); }
    if (t < 120) { int c = t / 40, w = t % 40; gwv[c][w] = sigmoidf_(F_w[c] * tv[w]); }
    __syncthreads();

    f16x4* Gp = (f16x4*)(G + b * 12032);
    for (int i = t; i < 3000; i += 256) {
        int flat = i * 4;
        int c = flat / 4000, rem = flat % 4000;
        int d = rem / 400, rem2 = rem % 400;
        int h = rem2 / 40, w0 = rem2 % 40;
        float gdh = gsv[c][d] * gsv[c][h];
        float4 v = xs4[i];
        f16x4 o;
        o[0] = (f16_t)(v.x * gdh * gwv[c][w0 + 0]);
        o[1] = (f16_t)(v.y * gdh * gwv[c][w0 + 1]);
        o[2] = (f16_t)(v.z * gdh * gwv[c][w0 + 2]);
        o[3] = (f16_t)(v.w * gdh * gwv[c][w0 + 3]);
        Gp[i] = o;
    }
    if (t < 8) Gp[3000 + t] = (f16x4){};   // zero pad K 12000->12032
}

// ---------------------------------------------------------------------------
// fp32 -> fp16 row convert with K padding 12000 -> 12032 (one block per row)
// ---------------------------------------------------------------------------
__global__ __launch_bounds__(256) void cvt_f16_pad(
    const float* __restrict__ in, f16_t* __restrict__ out) {
    const long r = blockIdx.x;
    const float4* ip = (const float4*)(in + r * 12000);
    f16x4* op = (f16x4*)(out + r * 12032);
    for (int i = threadIdx.x; i < 3000; i += 256) {
        float4 v = ip[i];
        f16x4 o;
        o[0] = (f16_t)v.x; o[1] = (f16_t)v.y; o[2] = (f16_t)v.z; o[3] = (f16_t)v.w;
        op[i] = o;
    }
    if (threadIdx.x < 8) op[3000 + threadIdx.x] = (f16x4){};
}

// ---------------------------------------------------------------------------
// fp32 -> fp16 convert, flat (n4 float4 chunks) — for w2
// ---------------------------------------------------------------------------
__global__ __launch_bounds__(256) void cvt_f16(
    const float* __restrict__ in, f16_t* __restrict__ out, long n4) {
    long stride = (long)gridDim.x * 256;
    for (long i = (long)blockIdx.x * 256 + threadIdx.x; i < n4; i += stride) {
        float4 v = ((const float4*)in)[i];
        f16x4 o;
        o[0] = (f16_t)v.x; o[1] = (f16_t)v.y; o[2] = (f16_t)v.z; o[3] = (f16_t)v.w;
        ((f16x4*)out)[i] = o;
    }
}

// ---------------------------------------------------------------------------
// GEMM1 (r7 structure, setprio removed — T5 is negative on lockstep GEMM,
// m190): 256x256 tile, BK=64, 8 waves, K-HALF phases, pipeline-ordered
// reads (bf00 first), compiler-scheduled lgkm, counted vmcnt(4) (T4),
// T2 swizzle. C[M,N] = relu(A[M,K2] @ B[N,K2]^T + bias[N]), f16 in/out.
// ---------------------------------------------------------------------------
__global__ __launch_bounds__(512, 2) void gemm1_kphase(
    const f16_t* __restrict__ A, const f16_t* __restrict__ B,
    const float* __restrict__ bias, f16_t* __restrict__ C,
    int M, int N, int K2, int NT) {
    __shared__ alignas(16) f16_t lds[65536];   // 128 KiB: 2 bufs x 32768 elems
    const int t = threadIdx.x;
    const int lane = t & 63, w = t >> 6;
    const int wr = w >> 2, wc = w & 3;
    const int l15 = lane & 15, lg = lane >> 4;
    const long tileM = (long)blockIdx.y * 256;
    const long tileN = (long)blockIdx.x * 256;
    const long lK2 = K2;

    const int srow = t >> 2;                           // 0..127
    const int gs8 = ((t & 3) ^ ((t >> 3) & 3)) * 8;    // swizzled global k-slot
    auto stage_half = [&](int dst, int ph, long kk) {
        f16_t* dA = lds + dst * 32768 + ph * 8192;
        f16_t* dB = dA + 16384;
        gload_lds16(A + (tileM + srow) * lK2 + kk + gs8, dA + t * 8);
        gload_lds16(A + (tileM + srow + 128) * lK2 + kk + gs8, dA + 4096 + t * 8);
        gload_lds16(B + (tileN + srow) * lK2 + kk + gs8, dB + t * 8);
        gload_lds16(B + (tileN + srow + 128) * lK2 + kk + gs8, dB + 4096 + t * 8);
    };

    const int sl8 = (lg ^ ((l15 >> 1) & 3)) * 8;

    f32x4 acc[8][4] = {};

    stage_half(0, 0, 0);
    stage_half(0, 1, 32);
    asm volatile("s_waitcnt vmcnt(4)" ::: "memory");
    __builtin_amdgcn_s_barrier();

    for (int kt = 0; kt < NT; ++kt) {
        const int c = kt & 1;
        const f16_t* bufc = lds + c * 32768;
        const bool more = (kt + 1 < NT);
        #pragma unroll
        for (int ph = 0; ph < 2; ++ph) {
            const f16_t* pa = bufc + ph * 8192;
            const f16_t* pb = bufc + 16384 + ph * 8192;
            f16x8 bf00 = *(const f16x8*)(pb + (wc * 64 + 0 + l15) * 32 + sl8);
            f16x8 af[2][4];
            #pragma unroll
            for (int qm = 0; qm < 2; ++qm)
                #pragma unroll
                for (int mf = 0; mf < 4; ++mf)
                    af[qm][mf] = *(const f16x8*)(pa +
                        (wr * 128 + qm * 64 + mf * 16 + l15) * 32 + sl8);
            f16x8 bf01 = *(const f16x8*)(pb + (wc * 64 + 16 + l15) * 32 + sl8);
            f16x8 bf10 = *(const f16x8*)(pb + (wc * 64 + 32 + l15) * 32 + sl8);
            f16x8 bf11 = *(const f16x8*)(pb + (wc * 64 + 48 + l15) * 32 + sl8);
            if (more) stage_half(c ^ 1, ph, (long)(kt + 1) * 64 + ph * 32);
            #pragma unroll
            for (int qm = 0; qm < 2; ++qm)
                #pragma unroll
                for (int mf = 0; mf < 4; ++mf)
                    acc[qm * 4 + mf][0] = __builtin_amdgcn_mfma_f32_16x16x32_f16(
                        af[qm][mf], bf00, acc[qm * 4 + mf][0], 0, 0, 0);
            #pragma unroll
            for (int qm = 0; qm < 2; ++qm)
                #pragma unroll
                for (int mf = 0; mf < 4; ++mf)
                    acc[qm * 4 + mf][1] = __builtin_amdgcn_mfma_f32_16x16x32_f16(
                        af[qm][mf], bf01, acc[qm * 4 + mf][1], 0, 0, 0);
            #pragma unroll
            for (int qm = 0; qm < 2; ++qm)
                #pragma unroll
                for (int mf = 0; mf < 4; ++mf)
                    acc[qm * 4 + mf][2] = __builtin_amdgcn_mfma_f32_16x16x32_f16(
                        af[qm][mf], bf10, acc[qm * 4 + mf][2], 0, 0, 0);
            #pragma unroll
            for (int qm = 0; qm < 2; ++qm)
                #pragma unroll
                for (int mf = 0; mf < 4; ++mf)
                    acc[qm * 4 + mf][3] = __builtin_amdgcn_mfma_f32_16x16x32_f16(
                        af[qm][mf], bf11, acc[qm * 4 + mf][3], 0, 0, 0);
            if (more) asm volatile("s_waitcnt vmcnt(4)" ::: "memory");
            else      asm volatile("s_waitcnt vmcnt(0)" ::: "memory");
            __builtin_amdgcn_s_barrier();
        }
    }

    const long rowC0 = tileM + wr * 128 + lg * 4;
    const long colC0 = tileN + wc * 64 + l15;
    #pragma unroll
    for (int ni = 0; ni < 4; ++ni) {
        long col = colC0 + ni * 16;
        float bia = bias[col];
        #pragma unroll
        for (int mi = 0; mi < 8; ++mi) {
            #pragma unroll
            for (int r = 0; r < 4; ++r) {
                long row = rowC0 + mi * 16 + r;
                float o = fmaxf(acc[mi][ni][r] + bia, 0.f);
                C[row * (long)N + col] = (f16_t)o;
            }
        }
    }
}

// ---------------------------------------------------------------------------
// GEMM2 split-K (m97 structure, 64x128 tile, BK=32): each K-chunk writes RAW
// partial sums to z2p[kc]. Grid (4, 64, 2) = 512 blocks -> 2 blocks/CU.
// ---------------------------------------------------------------------------
__global__ __launch_bounds__(256) void gemm2_splitk(
    const f16_t* __restrict__ A, const f16_t* __restrict__ B,
    float* __restrict__ Pp, int M, int N, int K, int KC) {
    __shared__ alignas(16) f16_t As[64 * 32];
    __shared__ alignas(16) f16_t Bs[128 * 32];
    const int t = threadIdx.x;
    const int lane = t & 63, wid = t >> 6;
    const int wr = wid >> 1, wc = wid & 1;
    const int l15 = lane & 15, lg = lane >> 4;
    const long rowA0 = (long)blockIdx.y * 64;
    const long colB0 = (long)blockIdx.x * 128;
    const int kc = blockIdx.z;
    const int k0 = kc * KC, k1 = k0 + KC;

    const int eA = t * 8;
    const int rA = eA >> 5, kA = eA & 31;
    const int eB0 = t * 8;
    const int rB0 = eB0 >> 5, kB0 = eB0 & 31;
    const int eB1 = eB0 + 2048;
    const int rB1 = eB1 >> 5, kB1 = eB1 & 31;

    int aoff[2], boff[4];
    #pragma unroll
    for (int m = 0; m < 2; ++m) aoff[m] = (wr * 32 + m * 16 + l15) * 32 + lg * 8;
    #pragma unroll
    for (int n = 0; n < 4; ++n) boff[n] = (wc * 64 + n * 16 + l15) * 32 + lg * 8;

    f32x4 acc[2][4] = {};

    for (int kk = k0; kk < k1; kk += 32) {
        __syncthreads();
        gload_lds16(A + (rowA0 + rA) * (long)K + kk + kA, As + eA);
        gload_lds16(B + (colB0 + rB0) * (long)K + kk + kB0, Bs + eB0);
        gload_lds16(B + (colB0 + rB1) * (long)K + kk + kB1, Bs + eB1);
        __syncthreads();

        f16x8 af[2], bfv[4];
        #pragma unroll
        for (int m = 0; m < 2; ++m) af[m] = *(const f16x8*)(As + aoff[m]);
        #pragma unroll
        for (int n = 0; n < 4; ++n) bfv[n] = *(const f16x8*)(Bs + boff[n]);
        #pragma unroll
        for (int m = 0; m < 2; ++m)
            #pragma unroll
            for (int n = 0; n < 4; ++n)
                acc[m][n] = __builtin_amdgcn_mfma_f32_16x16x32_f16(
                    af[m], bfv[n], acc[m][n], 0, 0, 0);
    }

    float* P = Pp + (long)kc * M * N;
    const long rowC0 = rowA0 + wr * 32 + lg * 4;
    const long colC0 = colB0 + wc * 64 + l15;
    #pragma unroll
    for (int n = 0; n < 4; ++n) {
        long col = colC0 + n * 16;
        #pragma unroll
        for (int m = 0; m < 2; ++m) {
            #pragma unroll
            for (int r = 0; r < 4; ++r) {
                long row = rowC0 + m * 16 + r;
                P[row * (long)N + col] = acc[m][n][r];
            }
        }
    }
}

// ---------------------------------------------------------------------------
// Head: z2 = relu(sum of 2 partials + b2); out = normalize(z2 @ w3^T + b3).
// One wave per row.
// ---------------------------------------------------------------------------
__global__ __launch_bounds__(256) void head_kernel(
    const float* __restrict__ Pp, const float* __restrict__ b2,
    const float* __restrict__ w3, const float* __restrict__ b3,
    float* __restrict__ out) {
    const int lane = threadIdx.x & 63, wid = threadIdx.x >> 6;
    const long b = (long)blockIdx.x * 4 + wid;
    const float4* p0 = (const float4*)(Pp + b * 512);
    const float4* p1 = (const float4*)(Pp + 2097152L + b * 512);
    const float4* bb = (const float4*)b2;
    float4 u0 = p0[lane * 2], u1 = p0[lane * 2 + 1];
    float4 v0 = p1[lane * 2], v1 = p1[lane * 2 + 1];
    float4 c0 = bb[lane * 2], c1 = bb[lane * 2 + 1];
    float4 z0, z1;
    z0.x = fmaxf(u0.x + v0.x + c0.x, 0.f); z0.y = fmaxf(u0.y + v0.y + c0.y, 0.f);
    z0.z = fmaxf(u0.z + v0.z + c0.z, 0.f); z0.w = fmaxf(u0.w + v0.w + c0.w, 0.f);
    z1.x = fmaxf(u1.x + v1.x + c1.x, 0.f); z1.y = fmaxf(u1.y + v1.y + c1.y, 0.f);
    z1.z = fmaxf(u1.z + v1.z + c1.z, 0.f); z1.w = fmaxf(u1.w + v1.w + c1.w, 0.f);
    float d[3];
    #pragma unroll
    for (int o = 0; o < 3; ++o) {
        const float4* wp = (const float4*)(w3 + o * 512);
        float4 a0 = wp[lane * 2], a1 = wp[lane * 2 + 1];
        d[o] = z0.x * a0.x + z0.y * a0.y + z0.z * a0.z + z0.w * a0.w +
               z1.x * a1.x + z1.y * a1.y + z1.z * a1.z + z1.w * a1.w;
    }
    #pragma unroll
    for (int o = 0; o < 3; ++o)
        #pragma unroll
        for (int off = 1; off < 64; off <<= 1) d[o] += __shfl_xor(d[o], off);
    float d0 = d[0] + b3[0], d1 = d[1] + b3[1], d2 = d[2] + b3[2];
    float nrm = fmaxf(sqrtf(d0 * d0 + d1 * d1 + d2 * d2), 1e-12f);
    if (lane < 3) {
        float v = (lane == 0) ? d0 : (lane == 1) ? d1 : d2;
        out[b * 3 + lane] = v / nrm;
    }
}

// ---------------------------------------------------------------------------
// Workspace layout (bytes), max 234.9 MB:
//   G   f16 4096x12032 :           0 ..  98,566,144
//   w1h f16 4096x12032 :  98,566,144 .. 197,132,288
//   z1  f16 4096x4096  : 197,132,288 .. 230,686,720
//   w2h f16  512x4096  : 230,686,720 .. 234,881,024
//   z2p f32 2x4096x512 :           0 ..  16,777,216  (overlaps dead G)
// ---------------------------------------------------------------------------
extern "C" void kernel_launch(void* const* d_in, const int* in_sizes, int n_in,
                              void* d_out, int out_size, void* d_ws, size_t ws_size,
                              hipStream_t stream) {
    const float* x      = (const float*)d_in[0];
    const float* conv_w = (const float*)d_in[1];
    const float* F_w    = (const float*)d_in[2];
    const float* w1     = (const float*)d_in[3];
    const float* b1     = (const float*)d_in[4];
    const float* w2     = (const float*)d_in[5];
    const float* b2     = (const float*)d_in[6];
    const float* w3     = (const float*)d_in[7];
    const float* b3     = (const float*)d_in[8];
    float* out = (float*)d_out;

    char* ws = (char*)d_ws;
    f16_t* G   = (f16_t*)(ws);
    f16_t* w1h = (f16_t*)(ws + 98566144L);
    f16_t* z1  = (f16_t*)(ws + 197132288L);
    f16_t* w2h = (f16_t*)(ws + 230686720L);
    float* z2p = (float*)(ws);             // overlaps G (dead after GEMM1)

    gate_kernel<<<4096, 256, 0, stream>>>(x, conv_w, F_w, G);
    cvt_f16_pad<<<4096, 256, 0, stream>>>(w1, w1h);
    cvt_f16<<<512, 256, 0, stream>>>(w2, w2h, 524288L);
    gemm1_kphase<<<dim3(16, 16), 512, 0, stream>>>(G, w1h, b1, z1, 4096, 4096, 12032, 188);
    gemm2_splitk<<<dim3(4, 64, 2), 256, 0, stream>>>(z1, w2h, z2p, 4096, 512, 4096, 2048);
    head_kernel<<<1024, 256, 0, stream>>>(z2p, b2, w3, b3, out);
}